// Round 1
// baseline (15205.231 us; speedup 1.0000x reference)
//
#include <hip/hip_runtime.h>

// EntityClassify (R-GCN, 2-layer) on MI355X — round 1: all-f32, push-mode atomics.
// acc[dst] += hw_r[src] * inv_deg_r[dst]  folds per-relation normalization into
// edge-scaled atomics so a single accumulator per layer suffices.

constexpr int NN   = 100000;
constexpr int RR   = 4;
constexpr int EE   = 800000;
constexpr int DIN  = 256;
constexpr int DH   = 64;
constexpr int DOUT = 16;

__global__ __launch_bounds__(256) void deg_count_kernel(const int* __restrict__ dst,
                                                        int* __restrict__ deg) {
  int idx = blockIdx.x * 256 + threadIdx.x;
  if (idx >= RR * EE) return;
  int r = idx / EE;
  atomicAdd(&deg[r * NN + dst[idx]], 1);
}

// In-place: buffer holds int degree counts; rewrite as float 1/max(deg,1).
__global__ __launch_bounds__(256) void inv_deg_kernel(void* __restrict__ buf) {
  int idx = blockIdx.x * 256 + threadIdx.x;
  if (idx >= RR * NN) return;
  int d = ((const int*)buf)[idx];
  ((float*)buf)[idx] = 1.0f / (float)(d > 1 ? d : 1);
}

// C[M,NC] = A[M,K] @ B[K,NC] (+bias). Block = 256 threads.
// Each thread: 4 rows x 16 cols of C. B staged in LDS (K-tiled at 128).
template <int K, int NC>
__global__ __launch_bounds__(256) void gemm_kernel(const float* __restrict__ A,
                                                   const float* __restrict__ B,
                                                   const float* __restrict__ bias,
                                                   float* __restrict__ C, int M) {
  constexpr int KT   = (K > 128) ? 128 : K;   // K-tile
  constexpr int NCG  = NC / 16;               // col groups of 16
  constexpr int TR   = 256 / NCG;             // thread-rows per slice
  constexpr int ROWS = TR * 4;                // rows per block
  __shared__ float Bs[KT * NC];

  const int t   = threadIdx.x;
  const int cg  = t % NCG;
  const int tr  = t / NCG;
  const int row0 = blockIdx.x * ROWS + tr;

  float acc[4][16];
#pragma unroll
  for (int i = 0; i < 4; ++i)
#pragma unroll
    for (int j = 0; j < 16; ++j) acc[i][j] = 0.f;

  for (int k0 = 0; k0 < K; k0 += KT) {
    if (k0 > 0) __syncthreads();
    for (int i = t; i < KT * NC / 4; i += 256)
      ((float4*)Bs)[i] = ((const float4*)(B + (size_t)k0 * NC))[i];
    __syncthreads();

#pragma unroll 2
    for (int k = 0; k < KT; k += 4) {
      float4 av[4];
#pragma unroll
      for (int i = 0; i < 4; ++i) {
        int r = row0 + i * TR;
        av[i] = (r < M) ? *(const float4*)(A + (size_t)r * K + k0 + k)
                        : make_float4(0.f, 0.f, 0.f, 0.f);
      }
#pragma unroll
      for (int kk = 0; kk < 4; ++kk) {
        const float4* brow = (const float4*)&Bs[(k + kk) * NC + cg * 16];
        float4 b0 = brow[0], b1 = brow[1], b2 = brow[2], b3 = brow[3];
        const float bb[16] = {b0.x, b0.y, b0.z, b0.w, b1.x, b1.y, b1.z, b1.w,
                              b2.x, b2.y, b2.z, b2.w, b3.x, b3.y, b3.z, b3.w};
#pragma unroll
        for (int i = 0; i < 4; ++i) {
          float a = (&av[i].x)[kk];
#pragma unroll
          for (int j = 0; j < 16; ++j) acc[i][j] = fmaf(a, bb[j], acc[i][j]);
        }
      }
    }
  }

#pragma unroll
  for (int i = 0; i < 4; ++i) {
    int r = row0 + i * TR;
    if (r >= M) continue;
    float* crow = C + (size_t)r * NC + cg * 16;
#pragma unroll
    for (int j = 0; j < 16; ++j) {
      float v = acc[i][j];
      if (bias) v += bias[cg * 16 + j];
      crow[j] = v;
    }
  }
}

// Per edge: acc[dst] += hw[src] * inv_deg[dst]  (DCH/16 threads per edge).
template <int DCH>
__global__ __launch_bounds__(256) void scatter_kernel(const float* __restrict__ hw,
                                                      const int* __restrict__ src,
                                                      const int* __restrict__ dst,
                                                      const float* __restrict__ invdeg,
                                                      float* __restrict__ acc, int E) {
  constexpr int SEG = DCH / 16;
  int idx = blockIdx.x * 256 + threadIdx.x;
  int e = idx / SEG, s = idx % SEG;
  if (e >= E) return;
  int sn = src[e], dn = dst[e];
  float w = invdeg[dn];
  const float4* g = (const float4*)(hw + (size_t)sn * DCH + s * 16);
  float4 v0 = g[0], v1 = g[1], v2 = g[2], v3 = g[3];
  float* a = acc + (size_t)dn * DCH + s * 16;
  unsafeAtomicAdd(a + 0,  v0.x * w);
  unsafeAtomicAdd(a + 1,  v0.y * w);
  unsafeAtomicAdd(a + 2,  v0.z * w);
  unsafeAtomicAdd(a + 3,  v0.w * w);
  unsafeAtomicAdd(a + 4,  v1.x * w);
  unsafeAtomicAdd(a + 5,  v1.y * w);
  unsafeAtomicAdd(a + 6,  v1.z * w);
  unsafeAtomicAdd(a + 7,  v1.w * w);
  unsafeAtomicAdd(a + 8,  v2.x * w);
  unsafeAtomicAdd(a + 9,  v2.y * w);
  unsafeAtomicAdd(a + 10, v2.z * w);
  unsafeAtomicAdd(a + 11, v2.w * w);
  unsafeAtomicAdd(a + 12, v3.x * w);
  unsafeAtomicAdd(a + 13, v3.y * w);
  unsafeAtomicAdd(a + 14, v3.z * w);
  unsafeAtomicAdd(a + 15, v3.w * w);
}

__global__ __launch_bounds__(256) void relu_kernel(float* __restrict__ h, int total4) {
  int idx = blockIdx.x * 256 + threadIdx.x;
  if (idx >= total4) return;
  float4 v = ((float4*)h)[idx];
  v.x = fmaxf(v.x, 0.f);
  v.y = fmaxf(v.y, 0.f);
  v.z = fmaxf(v.z, 0.f);
  v.w = fmaxf(v.w, 0.f);
  ((float4*)h)[idx] = v;
}

extern "C" void kernel_launch(void* const* d_in, const int* in_sizes, int n_in,
                              void* d_out, int out_size, void* d_ws, size_t ws_size,
                              hipStream_t stream) {
  const float* x   = (const float*)d_in[0];
  const int*   src = (const int*)d_in[1];
  const int*   dst = (const int*)d_in[2];
  const float* W1  = (const float*)d_in[3];
  const float* L1w = (const float*)d_in[4];
  const float* L1b = (const float*)d_in[5];
  const float* W2  = (const float*)d_in[6];
  const float* L2w = (const float*)d_in[7];
  const float* L2b = (const float*)d_in[8];
  float* out = (float*)d_out;

  // workspace layout
  const size_t hw_bytes  = (size_t)NN * DH * 4;   // 25.6 MB
  const size_t h_bytes   = (size_t)NN * DH * 4;   // 25.6 MB
  const size_t inv_bytes = (size_t)RR * NN * 4;   // 1.6 MB
  if (ws_size < hw_bytes + h_bytes + inv_bytes) return;  // fail loudly (poison stays)

  char* ws = (char*)d_ws;
  float* hwbuf = (float*)ws;
  float* h     = (float*)(ws + hw_bytes);
  void*  invd  = (void*)(ws + hw_bytes + h_bytes);
  float* invdf = (float*)invd;

  // degrees -> reciprocals (shared by both layers)
  hipMemsetAsync(invd, 0, inv_bytes, stream);
  deg_count_kernel<<<(RR * EE + 255) / 256, 256, 0, stream>>>(dst, (int*)invd);
  inv_deg_kernel<<<(RR * NN + 255) / 256, 256, 0, stream>>>(invd);

  // ---- layer 1 ----
  gemm_kernel<DIN, DH><<<(NN + 255) / 256, 256, 0, stream>>>(x, L1w, L1b, h, NN);
  for (int r = 0; r < RR; ++r) {
    gemm_kernel<DIN, DH><<<(NN + 255) / 256, 256, 0, stream>>>(
        x, W1 + (size_t)r * DIN * DH, nullptr, hwbuf, NN);
    scatter_kernel<DH><<<(EE * (DH / 16) + 255) / 256, 256, 0, stream>>>(
        hwbuf, src + (size_t)r * EE, dst + (size_t)r * EE, invdf + (size_t)r * NN, h, EE);
  }
  relu_kernel<<<(NN * DH / 4 + 255) / 256, 256, 0, stream>>>(h, NN * DH / 4);

  // ---- layer 2 ----
  gemm_kernel<DH, DOUT><<<(NN + 1023) / 1024, 256, 0, stream>>>(h, L2w, L2b, out, NN);
  for (int r = 0; r < RR; ++r) {
    gemm_kernel<DH, DOUT><<<(NN + 1023) / 1024, 256, 0, stream>>>(
        h, W2 + (size_t)r * DH * DOUT, nullptr, hwbuf, NN);
    scatter_kernel<DOUT><<<(EE + 255) / 256, 256, 0, stream>>>(
        hwbuf, src + (size_t)r * EE, dst + (size_t)r * EE, invdf + (size_t)r * NN, out, EE);
  }
}

// Round 2
// 1441.731 us; speedup vs baseline: 10.5465x; 10.5465x over previous
//
#include <hip/hip_runtime.h>

// EntityClassify (R-GCN, 2-layer) — round 2: pull-mode CSR aggregation.
// Round-1 post-mortem: push-mode f32 atomics = 51.2M memory-side atomic ops
// per relation (WRITE_SIZE 1.6GB, 2.94ms each). Replaced with device-built
// CSR (int atomics only) + gather-side accumulation (one owner-wave per node,
// non-atomic writes).

constexpr int NN   = 100000;
constexpr int RR   = 4;
constexpr int EE   = 800000;
constexpr int DIN  = 256;
constexpr int DH   = 64;
constexpr int DOUT = 16;
constexpr int RN   = RR * NN;
constexpr int RE   = RR * EE;

// ---------------- CSR build ----------------

__global__ __launch_bounds__(256) void deg_count_kernel(const int* __restrict__ dst,
                                                        int* __restrict__ deg) {
  int idx = blockIdx.x * 256 + threadIdx.x;
  if (idx >= RE) return;
  int r = idx / EE;
  atomicAdd(&deg[r * NN + dst[idx]], 1);
}

// per-256-block inclusive scan; block totals to aux
__global__ __launch_bounds__(256) void scan_block_kernel(const int* __restrict__ deg,
                                                         int* __restrict__ incl,
                                                         int* __restrict__ aux) {
  __shared__ int s[256];
  int t = threadIdx.x;
  int i = blockIdx.x * 256 + t;
  int v = (i < RN) ? deg[i] : 0;
  s[t] = v;
  __syncthreads();
  for (int off = 1; off < 256; off <<= 1) {
    int a = (t >= off) ? s[t - off] : 0;
    __syncthreads();
    s[t] += a;
    __syncthreads();
  }
  if (i < RN) incl[i] = s[t];
  if (t == 255) aux[blockIdx.x] = s[255];
}

__global__ void scan_aux_kernel(int* __restrict__ aux, int nb) {
  if (threadIdx.x != 0 || blockIdx.x != 0) return;
  int run = 0;
  for (int b = 0; b < nb; ++b) { int t = aux[b]; aux[b] = run; run += t; }
}

// incl -> exclusive base; cursor copy; invdeg
__global__ __launch_bounds__(256) void scan_apply_kernel(const int* __restrict__ deg,
                                                         int* __restrict__ base,
                                                         int* __restrict__ cursor,
                                                         float* __restrict__ invd,
                                                         const int* __restrict__ aux) {
  int i = blockIdx.x * 256 + threadIdx.x;
  if (i >= RN) return;
  int d = deg[i];
  int excl = base[i] - d + aux[blockIdx.x];
  base[i] = excl;
  cursor[i] = excl;
  invd[i] = 1.0f / (float)(d > 1 ? d : 1);
}

__global__ __launch_bounds__(256) void fill_csr_kernel(const int* __restrict__ src,
                                                       const int* __restrict__ dst,
                                                       int* __restrict__ cursor,
                                                       int* __restrict__ csr) {
  int idx = blockIdx.x * 256 + threadIdx.x;
  if (idx >= RE) return;
  int r = idx / EE;
  int pos = atomicAdd(&cursor[r * NN + dst[idx]], 1);
  csr[pos] = src[idx];
}

// ---------------- GEMM: C[M,NC] = A[M,K] @ B[K,NC] (+bias) ----------------
// 256 threads; RPT rows x 16 cols per thread; B tile staged in LDS.
template <int K, int NC, int RPT>
__global__ __launch_bounds__(256) void gemm_kernel(const float* __restrict__ A,
                                                   const float* __restrict__ B,
                                                   const float* __restrict__ bias,
                                                   float* __restrict__ C, int M) {
  constexpr int KT   = (K > 128) ? 128 : K;
  constexpr int NCG  = NC / 16;
  constexpr int TR   = 256 / NCG;
  constexpr int ROWS = TR * RPT;
  __shared__ float Bs[KT * NC];

  const int t = threadIdx.x;
  const int cg = t % NCG;
  const int tr = t / NCG;
  const int row0 = blockIdx.x * ROWS + tr;

  float acc[RPT][16];
#pragma unroll
  for (int i = 0; i < RPT; ++i)
#pragma unroll
    for (int j = 0; j < 16; ++j) acc[i][j] = 0.f;

  for (int k0 = 0; k0 < K; k0 += KT) {
    if (k0 > 0) __syncthreads();
    for (int i = t; i < KT * NC / 4; i += 256)
      ((float4*)Bs)[i] = ((const float4*)(B + (size_t)k0 * NC))[i];
    __syncthreads();

#pragma unroll 2
    for (int k = 0; k < KT; k += 4) {
      float4 av[RPT];
#pragma unroll
      for (int i = 0; i < RPT; ++i) {
        int r = row0 + i * TR;
        av[i] = (r < M) ? *(const float4*)(A + (size_t)r * K + k0 + k)
                        : make_float4(0.f, 0.f, 0.f, 0.f);
      }
#pragma unroll
      for (int kk = 0; kk < 4; ++kk) {
        const float4* brow = (const float4*)&Bs[(k + kk) * NC + cg * 16];
        float4 b0 = brow[0], b1 = brow[1], b2 = brow[2], b3 = brow[3];
        const float bb[16] = {b0.x, b0.y, b0.z, b0.w, b1.x, b1.y, b1.z, b1.w,
                              b2.x, b2.y, b2.z, b2.w, b3.x, b3.y, b3.z, b3.w};
#pragma unroll
        for (int i = 0; i < RPT; ++i) {
          float a = (&av[i].x)[kk];
#pragma unroll
          for (int j = 0; j < 16; ++j) acc[i][j] = fmaf(a, bb[j], acc[i][j]);
        }
      }
    }
  }

#pragma unroll
  for (int i = 0; i < RPT; ++i) {
    int r = row0 + i * TR;
    if (r >= M) continue;
    float* crow = C + (size_t)r * NC + cg * 16;
#pragma unroll
    for (int j = 0; j < 16; ++j) {
      float v = acc[i][j];
      if (bias) v += bias[cg * 16 + j];
      crow[j] = v;
    }
  }
}

// ---------------- pull-mode aggregation ----------------
// One wave per node; lane = channel (D=64). h[v] += invd * sum_e hw[src_e].
__global__ __launch_bounds__(256) void pull64_kernel(const float* __restrict__ hw,
                                                     const int* __restrict__ csr,
                                                     const int* __restrict__ base,
                                                     const int* __restrict__ deg,
                                                     const float* __restrict__ invd,
                                                     float* __restrict__ h, int rN) {
  int v = blockIdx.x * 4 + (threadIdx.x >> 6);
  if (v >= NN) return;
  int lane = threadIdx.x & 63;
  int idx = rN + v;
  int b0 = base[idx];
  int jend = b0 + deg[idx];
  float w = invd[idx];
  float acc = 0.f;
  int j = b0;
  for (; j + 3 < jend; j += 4) {
    int s0 = csr[j], s1 = csr[j + 1], s2 = csr[j + 2], s3 = csr[j + 3];
    float a0 = hw[(size_t)s0 * 64 + lane];
    float a1 = hw[(size_t)s1 * 64 + lane];
    float a2 = hw[(size_t)s2 * 64 + lane];
    float a3 = hw[(size_t)s3 * 64 + lane];
    acc += a0 + a1 + a2 + a3;
  }
  for (; j < jend; ++j) acc += hw[(size_t)csr[j] * 64 + lane];
  h[(size_t)v * 64 + lane] += acc * w;
}

// One wave per node; 4 edge-groups x 16 channels. out[v] += invd * sum hw2[src].
__global__ __launch_bounds__(256) void pull16_kernel(const float* __restrict__ hw,
                                                     const int* __restrict__ csr,
                                                     const int* __restrict__ base,
                                                     const int* __restrict__ deg,
                                                     const float* __restrict__ invd,
                                                     float* __restrict__ out, int rN) {
  int v = blockIdx.x * 4 + (threadIdx.x >> 6);
  if (v >= NN) return;
  int lane = threadIdx.x & 63;
  int c = lane & 15, g = lane >> 4;
  int idx = rN + v;
  int b0 = base[idx];
  int jend = b0 + deg[idx];
  float w = invd[idx];
  float acc = 0.f;
  for (int j = b0 + g; j < jend; j += 4)
    acc += hw[(size_t)csr[j] * 16 + c];
  acc += __shfl_xor(acc, 16);
  acc += __shfl_xor(acc, 32);
  if (lane < 16) out[(size_t)v * 16 + lane] += acc * w;
}

__global__ __launch_bounds__(256) void relu_kernel(float* __restrict__ h, int total4) {
  int idx = blockIdx.x * 256 + threadIdx.x;
  if (idx >= total4) return;
  float4 v = ((float4*)h)[idx];
  v.x = fmaxf(v.x, 0.f);
  v.y = fmaxf(v.y, 0.f);
  v.z = fmaxf(v.z, 0.f);
  v.w = fmaxf(v.w, 0.f);
  ((float4*)h)[idx] = v;
}

extern "C" void kernel_launch(void* const* d_in, const int* in_sizes, int n_in,
                              void* d_out, int out_size, void* d_ws, size_t ws_size,
                              hipStream_t stream) {
  const float* x   = (const float*)d_in[0];
  const int*   src = (const int*)d_in[1];
  const int*   dst = (const int*)d_in[2];
  const float* W1  = (const float*)d_in[3];
  const float* L1w = (const float*)d_in[4];
  const float* L1b = (const float*)d_in[5];
  const float* W2  = (const float*)d_in[6];
  const float* L2w = (const float*)d_in[7];
  const float* L2b = (const float*)d_in[8];
  float* out = (float*)d_out;

  // workspace layout (~70.4 MB)
  char* p = (char*)d_ws;
  const int nb = (RN + 255) / 256;
  float* hwbuf  = (float*)p; p += (size_t)NN * DH * 4;   // 25.6 MB (reused as hw2)
  float* h      = (float*)p; p += (size_t)NN * DH * 4;   // 25.6 MB
  int*   deg    = (int*)p;   p += (size_t)RN * 4;        // 1.6 MB
  int*   base   = (int*)p;   p += (size_t)RN * 4;        // 1.6 MB
  int*   cursor = (int*)p;   p += (size_t)RN * 4;        // 1.6 MB
  float* invd   = (float*)p; p += (size_t)RN * 4;        // 1.6 MB
  int*   aux    = (int*)p;   p += (size_t)nb * 4;        // ~6 KB
  int*   csr    = (int*)p;   p += (size_t)RE * 4;        // 12.8 MB
  if ((size_t)(p - (char*)d_ws) > ws_size) return;       // leaves poison -> visible fail

  // ---- CSR build ----
  hipMemsetAsync(deg, 0, (size_t)RN * 4, stream);
  deg_count_kernel<<<(RE + 255) / 256, 256, 0, stream>>>(dst, deg);
  scan_block_kernel<<<nb, 256, 0, stream>>>(deg, base, aux);
  scan_aux_kernel<<<1, 64, 0, stream>>>(aux, nb);
  scan_apply_kernel<<<nb, 256, 0, stream>>>(deg, base, cursor, invd, aux);
  fill_csr_kernel<<<(RE + 255) / 256, 256, 0, stream>>>(src, dst, cursor, csr);

  // ---- layer 1 ----
  gemm_kernel<DIN, DH, 1><<<(NN + 63) / 64, 256, 0, stream>>>(x, L1w, L1b, h, NN);
  for (int r = 0; r < RR; ++r) {
    gemm_kernel<DIN, DH, 1><<<(NN + 63) / 64, 256, 0, stream>>>(
        x, W1 + (size_t)r * DIN * DH, nullptr, hwbuf, NN);
    pull64_kernel<<<(NN + 3) / 4, 256, 0, stream>>>(hwbuf, csr, base, deg, invd, h, r * NN);
  }
  relu_kernel<<<(NN * DH / 4 + 255) / 256, 256, 0, stream>>>(h, NN * DH / 4);

  // ---- layer 2 ----
  gemm_kernel<DH, DOUT, 1><<<(NN + 255) / 256, 256, 0, stream>>>(h, L2w, L2b, out, NN);
  for (int r = 0; r < RR; ++r) {
    gemm_kernel<DH, DOUT, 1><<<(NN + 255) / 256, 256, 0, stream>>>(
        h, W2 + (size_t)r * DH * DOUT, nullptr, hwbuf, NN);
    pull16_kernel<<<(NN + 3) / 4, 256, 0, stream>>>(hwbuf, csr, base, deg, invd, out, r * NN);
  }
}

// Round 3
// 622.104 us; speedup vs baseline: 24.4416x; 2.3175x over previous
//
#include <hip/hip_runtime.h>

// EntityClassify (R-GCN) — round 3.
// r2 post-mortem: CSR build ~500us (two atomic passes + scan), f32 VALU GEMMs
// ~400us (5 dispatches), pulls ~360us. This round:
//  * one-pass padded CSR (CAP=32): cursor atomicAdd IS the degree count; scan
//    and deg pass eliminated. Dropped-slot prob ~4e-6 (Poisson(8) tail), and
//    normalization still uses the exact count.
//  * all 5 layer-1 GEMMs fused into ONE bf16 MFMA GEMM (N=320), ditto layer 2
//    (N=80). A-tiles converted f32->bf16 in-kernel; B pre-transposed once.
//    K-slot permutation invariance: A and B frags both loaded contiguous-8-k,
//    so the HW's internal k map doesn't matter. C/D map: col=lane&15,
//    row=4*(lane>>4)+reg (verified m89).
//  * message buffers bf16 -> pull gather traffic halved (128B/edge).
//  * relu folded into gemm2 A-staging; bias folded into epilogues.

constexpr int NN = 100000, RR = 4, EE = 800000;
constexpr int RN = RR * NN;
constexpr int CAP = 32;

typedef short bf16x8 __attribute__((ext_vector_type(8)));
typedef float f32x4 __attribute__((ext_vector_type(4)));

__device__ inline unsigned short f2bf(float f) {
  unsigned u = __float_as_uint(f);
  u += 0x7FFF + ((u >> 16) & 1);
  return (unsigned short)(u >> 16);
}
__device__ inline float bf2f(unsigned short s) {
  return __uint_as_float(((unsigned)s) << 16);
}

// ---- one-pass padded CSR: cursor counts true degree; first CAP srcs stored ----
__global__ __launch_bounds__(256) void fill_pad_kernel(const int* __restrict__ src,
                                                       const int* __restrict__ dst,
                                                       int* __restrict__ cursor,
                                                       int* __restrict__ csr_pad) {
  int r = blockIdx.y;
  int e = blockIdx.x * 256 + threadIdx.x;
  if (e >= EE) return;
  int idx = r * NN + dst[r * EE + e];
  int pos = atomicAdd(&cursor[idx], 1);
  if (pos < CAP) csr_pad[(size_t)idx * CAP + pos] = src[r * EE + e];
}

// ---- pre-transpose weights to bf16 [n][k]: BT1 [320][256], BT2 [80][64] ----
__global__ __launch_bounds__(256) void prep_w_kernel(const float* __restrict__ W1,
                                                     const float* __restrict__ L1w,
                                                     const float* __restrict__ W2,
                                                     const float* __restrict__ L2w,
                                                     unsigned short* __restrict__ BT1,
                                                     unsigned short* __restrict__ BT2) {
  int idx = blockIdx.x * 256 + threadIdx.x;
  if (idx < 320 * 256) {
    int n = idx >> 8, k = idx & 255;
    float v = (n < 256) ? W1[((size_t)((n >> 6) * 256 + k)) * 64 + (n & 63)]
                        : L1w[(size_t)k * 64 + (n - 256)];
    BT1[idx] = f2bf(v);
  } else {
    int j = idx - 320 * 256;
    if (j < 80 * 64) {
      int n = j >> 6, k = j & 63;
      float v = (n < 64) ? W2[((size_t)((n >> 4) * 64 + k)) * 16 + (n & 15)]
                         : L2w[(size_t)k * 16 + (n - 64)];
      BT2[j] = f2bf(v);
    }
  }
}

// ---- GEMM1: [1e5,320] = x[1e5,256] @ B; cols 0..255 -> hwcat bf16, 256..319 -> h f32 (+bias) ----
__global__ __launch_bounds__(512) void gemm1_kernel(const float* __restrict__ x,
                                                    const unsigned short* __restrict__ BT1,
                                                    const float* __restrict__ L1b,
                                                    unsigned short* __restrict__ hwcat,
                                                    float* __restrict__ h) {
  __shared__ char Al[128 * 64 * 2];  // [row][k] bf16, XOR-swizzled
  __shared__ char Bl[320 * 64 * 2];  // [n][k] bf16, XOR-swizzled
  const int t = threadIdx.x;
  const int m0 = blockIdx.x * 128;
  const int wid = t >> 6, lane = t & 63;
  const int wm = wid >> 2, wn = wid & 3;  // 2 x 4 wave grid
  const int l15 = lane & 15, g = lane >> 4;

  f32x4 acc[4][5];
#pragma unroll
  for (int i = 0; i < 4; ++i)
#pragma unroll
    for (int j = 0; j < 5; ++j) acc[i][j] = (f32x4){0.f, 0.f, 0.f, 0.f};

  for (int kc = 0; kc < 4; ++kc) {
    if (kc) __syncthreads();
    // stage A: 128 rows x 64 k, f32 -> bf16
#pragma unroll
    for (int it = 0; it < 4; ++it) {
      int fl = t + 512 * it;
      int row = fl >> 4, kq = (fl & 15) * 4;
      int rg = m0 + row;
      float4 v = (rg < NN) ? *(const float4*)(x + (size_t)rg * 256 + kc * 64 + kq)
                           : make_float4(0.f, 0.f, 0.f, 0.f);
      ushort4 p = {f2bf(v.x), f2bf(v.y), f2bf(v.z), f2bf(v.w)};
      int wb = ((row * 64 + kq) * 2) ^ ((row & 7) << 4);
      *(ushort4*)(Al + wb) = p;
    }
    // stage B tile: 320 rows x 64 k (bf16 already)
#pragma unroll
    for (int it = 0; it < 5; ++it) {
      int fl = t + 512 * it;
      int n = fl >> 3, i8 = (fl & 7) * 8;
      uint4 u = *(const uint4*)(BT1 + (size_t)n * 256 + kc * 64 + i8);
      int wb = ((n * 64 + i8) * 2) ^ ((n & 7) << 4);
      *(uint4*)(Bl + wb) = u;
    }
    __syncthreads();
#pragma unroll
    for (int ks = 0; ks < 2; ++ks) {
      bf16x8 af[4], bfr[5];
#pragma unroll
      for (int mi = 0; mi < 4; ++mi) {
        int row = wm * 64 + mi * 16 + l15;
        int byte = ((row * 64 + ks * 32 + g * 8) * 2) ^ ((row & 7) << 4);
        af[mi] = *(const bf16x8*)(Al + byte);
      }
#pragma unroll
      for (int ni = 0; ni < 5; ++ni) {
        int n = wn * 80 + ni * 16 + l15;
        int byte = ((n * 64 + ks * 32 + g * 8) * 2) ^ ((n & 7) << 4);
        bfr[ni] = *(const bf16x8*)(Bl + byte);
      }
#pragma unroll
      for (int mi = 0; mi < 4; ++mi)
#pragma unroll
        for (int ni = 0; ni < 5; ++ni)
          acc[mi][ni] = __builtin_amdgcn_mfma_f32_16x16x32_bf16(af[mi], bfr[ni], acc[mi][ni], 0, 0, 0);
    }
  }
#pragma unroll
  for (int mi = 0; mi < 4; ++mi) {
    int rbase = m0 + wm * 64 + mi * 16 + 4 * g;
#pragma unroll
    for (int ni = 0; ni < 5; ++ni) {
      int n0 = wn * 80 + ni * 16;
      int n = n0 + l15;
#pragma unroll
      for (int e = 0; e < 4; ++e) {
        int row = rbase + e;
        if (row >= NN) continue;
        float v = acc[mi][ni][e];
        if (n0 < 256) hwcat[(size_t)row * 256 + n] = f2bf(v);
        else h[(size_t)row * 64 + (n - 256)] = v + L1b[n - 256];
      }
    }
  }
}

// ---- pull layer1: h[v] (self) += sum_r invdeg_r * sum_e hwcat[src_e, r*64+lane] ----
__global__ __launch_bounds__(256) void pull64_kernel(const unsigned short* __restrict__ hwcat,
                                                     const int* __restrict__ csr_pad,
                                                     const int* __restrict__ cursor,
                                                     float* __restrict__ h) {
  int v = blockIdx.x * 4 + (threadIdx.x >> 6);
  if (v >= NN) return;
  int lane = threadIdx.x & 63;
  float hval = h[(size_t)v * 64 + lane];
  for (int r = 0; r < RR; ++r) {
    int idx = r * NN + v;
    int d = cursor[idx];
    int dd = d < CAP ? d : CAP;
    float w = 1.0f / (float)(d > 1 ? d : 1);
    const int* lst = csr_pad + (size_t)idx * CAP;
    float acc = 0.f;
    int i = 0;
    for (; i + 4 <= dd; i += 4) {
      int s0 = lst[i], s1 = lst[i + 1], s2 = lst[i + 2], s3 = lst[i + 3];
      acc += bf2f(hwcat[(size_t)s0 * 256 + r * 64 + lane]);
      acc += bf2f(hwcat[(size_t)s1 * 256 + r * 64 + lane]);
      acc += bf2f(hwcat[(size_t)s2 * 256 + r * 64 + lane]);
      acc += bf2f(hwcat[(size_t)s3 * 256 + r * 64 + lane]);
    }
    for (; i < dd; ++i) acc += bf2f(hwcat[(size_t)lst[i] * 256 + r * 64 + lane]);
    hval += acc * w;
  }
  h[(size_t)v * 64 + lane] = hval;
}

// ---- GEMM2: [1e5,80] = relu(h)[1e5,64] @ B2; cols 0..63 -> hw2 bf16, 64..79 -> out f32 (+bias) ----
__global__ __launch_bounds__(512) void gemm2_kernel(const float* __restrict__ h,
                                                    const unsigned short* __restrict__ BT2,
                                                    const float* __restrict__ L2b,
                                                    unsigned short* __restrict__ hw2,
                                                    float* __restrict__ out) {
  __shared__ char Al[256 * 64 * 2];
  __shared__ char Bl[80 * 64 * 2];
  const int t = threadIdx.x;
  const int m0 = blockIdx.x * 256;
  const int wid = t >> 6, lane = t & 63;
  const int l15 = lane & 15, g = lane >> 4;

  f32x4 acc[2][5];
#pragma unroll
  for (int i = 0; i < 2; ++i)
#pragma unroll
    for (int j = 0; j < 5; ++j) acc[i][j] = (f32x4){0.f, 0.f, 0.f, 0.f};

#pragma unroll
  for (int it = 0; it < 8; ++it) {
    int fl = t + 512 * it;
    int row = fl >> 4, kq = (fl & 15) * 4;
    int rg = m0 + row;
    float4 v = (rg < NN) ? *(const float4*)(h + (size_t)rg * 64 + kq)
                         : make_float4(0.f, 0.f, 0.f, 0.f);
    ushort4 p = {f2bf(fmaxf(v.x, 0.f)), f2bf(fmaxf(v.y, 0.f)),
                 f2bf(fmaxf(v.z, 0.f)), f2bf(fmaxf(v.w, 0.f))};
    int wb = ((row * 64 + kq) * 2) ^ ((row & 7) << 4);
    *(ushort4*)(Al + wb) = p;
  }
#pragma unroll
  for (int it = 0; it < 2; ++it) {
    int fl = t + 512 * it;
    if (fl < 640) {
      int n = fl >> 3, i8 = (fl & 7) * 8;
      uint4 u = *(const uint4*)(BT2 + (size_t)n * 64 + i8);
      int wb = ((n * 64 + i8) * 2) ^ ((n & 7) << 4);
      *(uint4*)(Bl + wb) = u;
    }
  }
  __syncthreads();
#pragma unroll
  for (int ks = 0; ks < 2; ++ks) {
    bf16x8 af[2], bfr[5];
#pragma unroll
    for (int mi = 0; mi < 2; ++mi) {
      int row = wid * 32 + mi * 16 + l15;
      int byte = ((row * 64 + ks * 32 + g * 8) * 2) ^ ((row & 7) << 4);
      af[mi] = *(const bf16x8*)(Al + byte);
    }
#pragma unroll
    for (int ni = 0; ni < 5; ++ni) {
      int n = ni * 16 + l15;
      int byte = ((n * 64 + ks * 32 + g * 8) * 2) ^ ((n & 7) << 4);
      bfr[ni] = *(const bf16x8*)(Bl + byte);
    }
#pragma unroll
    for (int mi = 0; mi < 2; ++mi)
#pragma unroll
      for (int ni = 0; ni < 5; ++ni)
        acc[mi][ni] = __builtin_amdgcn_mfma_f32_16x16x32_bf16(af[mi], bfr[ni], acc[mi][ni], 0, 0, 0);
  }
#pragma unroll
  for (int mi = 0; mi < 2; ++mi) {
    int rbase = m0 + wid * 32 + mi * 16 + 4 * g;
#pragma unroll
    for (int ni = 0; ni < 5; ++ni) {
      int n0 = ni * 16;
      int n = n0 + l15;
#pragma unroll
      for (int e = 0; e < 4; ++e) {
        int row = rbase + e;
        if (row >= NN) continue;
        float v = acc[mi][ni][e];
        if (n0 < 64) hw2[(size_t)row * 64 + n] = f2bf(v);
        else out[(size_t)row * 16 + (n - 64)] = v + L2b[n - 64];
      }
    }
  }
}

// ---- pull layer2: out[v] += sum_r invdeg_r * sum_e hw2[src_e, r*16+c] ----
__global__ __launch_bounds__(256) void pull16_kernel(const unsigned short* __restrict__ hw2,
                                                     const int* __restrict__ csr_pad,
                                                     const int* __restrict__ cursor,
                                                     float* __restrict__ out) {
  int v = blockIdx.x * 4 + (threadIdx.x >> 6);
  if (v >= NN) return;
  int lane = threadIdx.x & 63;
  int c = lane & 15, g = lane >> 4;
  float tot = 0.f;
  for (int r = 0; r < RR; ++r) {
    int idx = r * NN + v;
    int d = cursor[idx];
    int dd = d < CAP ? d : CAP;
    float w = 1.0f / (float)(d > 1 ? d : 1);
    const int* lst = csr_pad + (size_t)idx * CAP;
    float acc = 0.f;
    for (int i = g; i < dd; i += 4) acc += bf2f(hw2[(size_t)lst[i] * 64 + r * 16 + c]);
    acc += __shfl_xor(acc, 16);
    acc += __shfl_xor(acc, 32);
    tot += acc * w;
  }
  if (lane < 16) out[(size_t)v * 16 + lane] += tot;
}

extern "C" void kernel_launch(void* const* d_in, const int* in_sizes, int n_in,
                              void* d_out, int out_size, void* d_ws, size_t ws_size,
                              hipStream_t stream) {
  const float* x   = (const float*)d_in[0];
  const int*   src = (const int*)d_in[1];
  const int*   dst = (const int*)d_in[2];
  const float* W1  = (const float*)d_in[3];
  const float* L1w = (const float*)d_in[4];
  const float* L1b = (const float*)d_in[5];
  const float* W2  = (const float*)d_in[6];
  const float* L2w = (const float*)d_in[7];
  const float* L2b = (const float*)d_in[8];
  float* out = (float*)d_out;

  char* p = (char*)d_ws;
  int* csr_pad = (int*)p;            p += (size_t)RN * CAP * 4;   // 51.2 MB
  int* cursor  = (int*)p;            p += (size_t)RN * 4;         // 1.6 MB
  unsigned short* hwcat = (unsigned short*)p; p += (size_t)NN * 256 * 2;  // 51.2 MB
  float* h = (float*)p;              p += (size_t)NN * 64 * 4;    // 25.6 MB
  unsigned short* BT1 = (unsigned short*)p; p += 320 * 256 * 2;
  unsigned short* BT2 = (unsigned short*)p; p += 80 * 64 * 2;
  if ((size_t)(p - (char*)d_ws) > ws_size) return;  // visible fail (poison stays)
  unsigned short* hw2 = hwcat;  // overlay: hwcat dead after pull64

  hipMemsetAsync(cursor, 0, (size_t)RN * 4, stream);
  fill_pad_kernel<<<dim3((EE + 255) / 256, RR), 256, 0, stream>>>(src, dst, cursor, csr_pad);
  prep_w_kernel<<<(320 * 256 + 80 * 64 + 255) / 256, 256, 0, stream>>>(W1, L1w, W2, L2w, BT1, BT2);
  gemm1_kernel<<<(NN + 127) / 128, 512, 0, stream>>>(x, BT1, L1b, hwcat, h);
  pull64_kernel<<<(NN + 3) / 4, 256, 0, stream>>>(hwcat, csr_pad, cursor, h);
  gemm2_kernel<<<(NN + 255) / 256, 512, 0, stream>>>(h, BT2, L2b, hw2, out);
  pull16_kernel<<<(NN + 3) / 4, 256, 0, stream>>>(hw2, csr_pad, cursor, out);
}

// Round 4
// 612.232 us; speedup vs baseline: 24.8357x; 1.0161x over previous
//
#include <hip/hip_runtime.h>

// EntityClassify (R-GCN) — round 4: overlap-oriented fusion.
// r3 post-mortem: fill_pad = 281us (45% of total), transaction-bound (3.2M
// atomics + 3.2M scattered 4B writes, 32B each, VALUBusy 0.4%), irreducible.
// So: overlap it. fused1 = fill + gemm1 in one kernel (1-in-5 blocks are GEMM
// tiles, rest are fill; gemm M-tile 64 so LDS=48KB keeps 3 blocks/CU).
// pullgemm2 = pull64 folded into gemm2 A-staging (each block pulls its own
// 256 rows; relu+bf16 into LDS; h round-trip eliminated; gather overlaps MFMA
// across blocks). hw2 gets its own buffer (hwcat still live in pullgemm2).

constexpr int NN = 100000, RR = 4, EE = 800000;
constexpr int RN = RR * NN;
constexpr int CAP = 32;
constexpr int NG1 = (NN + 63) / 64;     // 1563 gemm1 tiles (M=64)
constexpr int NF  = RR * EE / 512;      // 6250 fill blocks (exact)

typedef short bf16x8 __attribute__((ext_vector_type(8)));
typedef float f32x4 __attribute__((ext_vector_type(4)));

__device__ inline unsigned short f2bf(float f) {
  unsigned u = __float_as_uint(f);
  u += 0x7FFF + ((u >> 16) & 1);
  return (unsigned short)(u >> 16);
}
__device__ inline float bf2f(unsigned short s) {
  return __uint_as_float(((unsigned)s) << 16);
}

// ---- weights -> bf16 [n][k]: BT1 [320][256], BT2 [80][64] ----
__global__ __launch_bounds__(256) void prep_w_kernel(const float* __restrict__ W1,
                                                     const float* __restrict__ L1w,
                                                     const float* __restrict__ W2,
                                                     const float* __restrict__ L2w,
                                                     unsigned short* __restrict__ BT1,
                                                     unsigned short* __restrict__ BT2) {
  int idx = blockIdx.x * 256 + threadIdx.x;
  if (idx < 320 * 256) {
    int n = idx >> 8, k = idx & 255;
    float v = (n < 256) ? W1[((size_t)((n >> 6) * 256 + k)) * 64 + (n & 63)]
                        : L1w[(size_t)k * 64 + (n - 256)];
    BT1[idx] = f2bf(v);
  } else {
    int j = idx - 320 * 256;
    if (j < 80 * 64) {
      int n = j >> 6, k = j & 63;
      float v = (n < 64) ? W2[((size_t)((n >> 4) * 64 + k)) * 16 + (n & 15)]
                         : L2w[(size_t)k * 16 + (n - 64)];
      BT2[j] = f2bf(v);
    }
  }
}

// ---- fused1: fill (padded CSR) + gemm1 ([1e5,320] = x @ BT1^T) ----
// blocks with bid%5==0 && bid/5<NG1 are GEMM tiles; the rest are fill.
__global__ __launch_bounds__(512) void fused1_kernel(const float* __restrict__ x,
                                                     const unsigned short* __restrict__ BT1,
                                                     const float* __restrict__ L1b,
                                                     const int* __restrict__ src,
                                                     const int* __restrict__ dst,
                                                     int* __restrict__ cursor,
                                                     int* __restrict__ csr_pad,
                                                     unsigned short* __restrict__ hwcat,
                                                     float* __restrict__ h) {
  __shared__ char Al[64 * 64 * 2];    // 8 KB
  __shared__ char Bl[320 * 64 * 2];   // 40 KB
  const int bid = blockIdx.x;
  const bool is_gemm = (bid % 5 == 0) && (bid / 5 < NG1);

  if (!is_gemm) {
    // ---- fill role: one edge per thread ----
    int cnt = (bid + 4) / 5;            // # gemm blocks with id < bid
    if (cnt > NG1) cnt = NG1;
    int fid = bid - cnt;                // 0..NF-1
    int fl = fid * 512 + threadIdx.x;   // 0..RR*EE-1 (exact)
    int r = fl / EE;
    int idx = r * NN + dst[fl];
    int pos = atomicAdd(&cursor[idx], 1);
    if (pos < CAP) csr_pad[(size_t)idx * CAP + pos] = src[fl];
    return;
  }

  // ---- gemm role: M-tile 64, N=320, K=256 ----
  const int t = threadIdx.x;
  const int m0 = (bid / 5) * 64;
  const int wid = t >> 6, lane = t & 63;
  const int wm = wid >> 2, wn = wid & 3;   // 2 x 4 wave grid
  const int l15 = lane & 15, g = lane >> 4;

  f32x4 acc[2][5];
#pragma unroll
  for (int i = 0; i < 2; ++i)
#pragma unroll
    for (int j = 0; j < 5; ++j) acc[i][j] = (f32x4){0.f, 0.f, 0.f, 0.f};

  for (int kc = 0; kc < 4; ++kc) {
    if (kc) __syncthreads();
    // stage A: 64 rows x 64 k, f32 -> bf16
#pragma unroll
    for (int it = 0; it < 2; ++it) {
      int fl = t + 512 * it;
      int row = fl >> 4, kq = (fl & 15) * 4;
      int rg = m0 + row;
      float4 v = (rg < NN) ? *(const float4*)(x + (size_t)rg * 256 + kc * 64 + kq)
                           : make_float4(0.f, 0.f, 0.f, 0.f);
      ushort4 pck = {f2bf(v.x), f2bf(v.y), f2bf(v.z), f2bf(v.w)};
      int wb = ((row * 64 + kq) * 2) ^ ((row & 7) << 4);
      *(ushort4*)(Al + wb) = pck;
    }
    // stage B: 320 n-rows x 64 k
#pragma unroll
    for (int it = 0; it < 5; ++it) {
      int fl = t + 512 * it;
      int n = fl >> 3, i8 = (fl & 7) * 8;
      uint4 u = *(const uint4*)(BT1 + (size_t)n * 256 + kc * 64 + i8);
      int wb = ((n * 64 + i8) * 2) ^ ((n & 7) << 4);
      *(uint4*)(Bl + wb) = u;
    }
    __syncthreads();
#pragma unroll
    for (int ks = 0; ks < 2; ++ks) {
      bf16x8 af[2], bfr[5];
#pragma unroll
      for (int mi = 0; mi < 2; ++mi) {
        int row = wm * 32 + mi * 16 + l15;
        int byte = ((row * 64 + ks * 32 + g * 8) * 2) ^ ((row & 7) << 4);
        af[mi] = *(const bf16x8*)(Al + byte);
      }
#pragma unroll
      for (int ni = 0; ni < 5; ++ni) {
        int n = wn * 80 + ni * 16 + l15;
        int byte = ((n * 64 + ks * 32 + g * 8) * 2) ^ ((n & 7) << 4);
        bfr[ni] = *(const bf16x8*)(Bl + byte);
      }
#pragma unroll
      for (int mi = 0; mi < 2; ++mi)
#pragma unroll
        for (int ni = 0; ni < 5; ++ni)
          acc[mi][ni] = __builtin_amdgcn_mfma_f32_16x16x32_bf16(af[mi], bfr[ni], acc[mi][ni], 0, 0, 0);
    }
  }
#pragma unroll
  for (int mi = 0; mi < 2; ++mi) {
    int rbase = m0 + wm * 32 + mi * 16 + 4 * g;
#pragma unroll
    for (int ni = 0; ni < 5; ++ni) {
      int n0 = wn * 80 + ni * 16;
      int n = n0 + l15;
#pragma unroll
      for (int e = 0; e < 4; ++e) {
        int row = rbase + e;
        if (row >= NN) continue;
        float v = acc[mi][ni][e];
        if (n0 < 256) hwcat[(size_t)row * 256 + n] = f2bf(v);
        else h[(size_t)row * 64 + (n - 256)] = v + L1b[n - 256];
      }
    }
  }
}

// ---- pullgemm2: per block, pull 256 rows (agg + self + relu -> bf16 LDS),
//      then [256,80] = A @ BT2^T; cols 0..63 -> hw2, 64..79 -> out (+bias) ----
__global__ __launch_bounds__(512) void pullgemm2_kernel(const float* __restrict__ h,
                                                        const unsigned short* __restrict__ hwcat,
                                                        const int* __restrict__ csr_pad,
                                                        const int* __restrict__ cursor,
                                                        const unsigned short* __restrict__ BT2,
                                                        const float* __restrict__ L2b,
                                                        unsigned short* __restrict__ hw2,
                                                        float* __restrict__ out) {
  __shared__ char Al[256 * 64 * 2];   // 32 KB
  __shared__ char Bl[80 * 64 * 2];    // 10 KB
  const int t = threadIdx.x;
  const int m0 = blockIdx.x * 256;
  const int wid = t >> 6, lane = t & 63;
  const int l15 = lane & 15, g = lane >> 4;

  // phase 1: each wave pulls rows wid*32 .. wid*32+31
  for (int i = 0; i < 32; ++i) {
    int row = wid * 32 + i;
    int v = m0 + row;
    float hval = 0.f;
    if (v < NN) {
      hval = h[(size_t)v * 64 + lane];
#pragma unroll
      for (int r = 0; r < RR; ++r) {
        int idx = r * NN + v;
        int dcount = cursor[idx];
        int dd = dcount < CAP ? dcount : CAP;
        float w = 1.0f / (float)(dcount > 1 ? dcount : 1);
        const int* lst = csr_pad + (size_t)idx * CAP;
        float a = 0.f;
        int j = 0;
        for (; j + 4 <= dd; j += 4) {
          int s0 = lst[j], s1 = lst[j + 1], s2 = lst[j + 2], s3 = lst[j + 3];
          a += bf2f(hwcat[(size_t)s0 * 256 + r * 64 + lane]);
          a += bf2f(hwcat[(size_t)s1 * 256 + r * 64 + lane]);
          a += bf2f(hwcat[(size_t)s2 * 256 + r * 64 + lane]);
          a += bf2f(hwcat[(size_t)s3 * 256 + r * 64 + lane]);
        }
        for (; j < dd; ++j) a += bf2f(hwcat[(size_t)lst[j] * 256 + r * 64 + lane]);
        hval += a * w;
      }
      hval = fmaxf(hval, 0.f);
    }
    int wb = ((row * 64 + lane) * 2) ^ ((row & 7) << 4);
    *(unsigned short*)(Al + wb) = f2bf(hval);
  }
  // stage B
#pragma unroll
  for (int it = 0; it < 2; ++it) {
    int fl = t + 512 * it;
    if (fl < 640) {
      int n = fl >> 3, i8 = (fl & 7) * 8;
      uint4 u = *(const uint4*)(BT2 + (size_t)n * 64 + i8);
      int wb = ((n * 64 + i8) * 2) ^ ((n & 7) << 4);
      *(uint4*)(Bl + wb) = u;
    }
  }
  __syncthreads();

  f32x4 acc[2][5];
#pragma unroll
  for (int i = 0; i < 2; ++i)
#pragma unroll
    for (int j = 0; j < 5; ++j) acc[i][j] = (f32x4){0.f, 0.f, 0.f, 0.f};
#pragma unroll
  for (int ks = 0; ks < 2; ++ks) {
    bf16x8 af[2], bfr[5];
#pragma unroll
    for (int mi = 0; mi < 2; ++mi) {
      int row = wid * 32 + mi * 16 + l15;
      int byte = ((row * 64 + ks * 32 + g * 8) * 2) ^ ((row & 7) << 4);
      af[mi] = *(const bf16x8*)(Al + byte);
    }
#pragma unroll
    for (int ni = 0; ni < 5; ++ni) {
      int n = ni * 16 + l15;
      int byte = ((n * 64 + ks * 32 + g * 8) * 2) ^ ((n & 7) << 4);
      bfr[ni] = *(const bf16x8*)(Bl + byte);
    }
#pragma unroll
    for (int mi = 0; mi < 2; ++mi)
#pragma unroll
      for (int ni = 0; ni < 5; ++ni)
        acc[mi][ni] = __builtin_amdgcn_mfma_f32_16x16x32_bf16(af[mi], bfr[ni], acc[mi][ni], 0, 0, 0);
  }
#pragma unroll
  for (int mi = 0; mi < 2; ++mi) {
    int rbase = m0 + wid * 32 + mi * 16 + 4 * g;
#pragma unroll
    for (int ni = 0; ni < 5; ++ni) {
      int n0 = ni * 16;
      int n = n0 + l15;
#pragma unroll
      for (int e = 0; e < 4; ++e) {
        int row = rbase + e;
        if (row >= NN) continue;
        float v = acc[mi][ni][e];
        if (n0 < 64) hw2[(size_t)row * 64 + n] = f2bf(v);
        else out[(size_t)row * 16 + (n - 64)] = v + L2b[n - 64];
      }
    }
  }
}

// ---- pull layer2: out[v] += sum_r invdeg_r * sum_e hw2[src_e, r*16+c] ----
__global__ __launch_bounds__(256) void pull16_kernel(const unsigned short* __restrict__ hw2,
                                                     const int* __restrict__ csr_pad,
                                                     const int* __restrict__ cursor,
                                                     float* __restrict__ out) {
  int v = blockIdx.x * 4 + (threadIdx.x >> 6);
  if (v >= NN) return;
  int lane = threadIdx.x & 63;
  int c = lane & 15, g = lane >> 4;
  float tot = 0.f;
#pragma unroll
  for (int r = 0; r < RR; ++r) {
    int idx = r * NN + v;
    int d = cursor[idx];
    int dd = d < CAP ? d : CAP;
    float w = 1.0f / (float)(d > 1 ? d : 1);
    const int* lst = csr_pad + (size_t)idx * CAP;
    float acc = 0.f;
    for (int i = g; i < dd; i += 4) acc += bf2f(hw2[(size_t)lst[i] * 64 + r * 16 + c]);
    acc += __shfl_xor(acc, 16);
    acc += __shfl_xor(acc, 32);
    tot += acc * w;
  }
  if (lane < 16) out[(size_t)v * 16 + lane] += tot;
}

extern "C" void kernel_launch(void* const* d_in, const int* in_sizes, int n_in,
                              void* d_out, int out_size, void* d_ws, size_t ws_size,
                              hipStream_t stream) {
  const float* x   = (const float*)d_in[0];
  const int*   src = (const int*)d_in[1];
  const int*   dst = (const int*)d_in[2];
  const float* W1  = (const float*)d_in[3];
  const float* L1w = (const float*)d_in[4];
  const float* L1b = (const float*)d_in[5];
  const float* W2  = (const float*)d_in[6];
  const float* L2w = (const float*)d_in[7];
  const float* L2b = (const float*)d_in[8];
  float* out = (float*)d_out;

  char* p = (char*)d_ws;
  int* csr_pad = (int*)p;                     p += (size_t)RN * CAP * 4;      // 51.2 MB
  int* cursor  = (int*)p;                     p += (size_t)RN * 4;            // 1.6 MB
  unsigned short* hwcat = (unsigned short*)p; p += (size_t)NN * 256 * 2;      // 51.2 MB
  float* h = (float*)p;                       p += (size_t)NN * 64 * 4;       // 25.6 MB
  unsigned short* hw2 = (unsigned short*)p;   p += (size_t)NN * 64 * 2;       // 12.8 MB
  unsigned short* BT1 = (unsigned short*)p;   p += 320 * 256 * 2;
  unsigned short* BT2 = (unsigned short*)p;   p += 80 * 64 * 2;
  if ((size_t)(p - (char*)d_ws) > ws_size) return;  // visible fail (poison stays)

  hipMemsetAsync(cursor, 0, (size_t)RN * 4, stream);
  prep_w_kernel<<<(320 * 256 + 80 * 64 + 255) / 256, 256, 0, stream>>>(W1, L1w, W2, L2w, BT1, BT2);
  fused1_kernel<<<NG1 + NF, 512, 0, stream>>>(x, BT1, L1b, src, dst, cursor, csr_pad, hwcat, h);
  pullgemm2_kernel<<<(NN + 255) / 256, 512, 0, stream>>>(h, hwcat, csr_pad, cursor, BT2, L2b, hw2, out);
  pull16_kernel<<<(NN + 3) / 4, 256, 0, stream>>>(hw2, csr_pad, cursor, out);
}

// Round 5
// 595.111 us; speedup vs baseline: 25.5503x; 1.0288x over previous
//
#include <hip/hip_runtime.h>

// EntityClassify (R-GCN) — round 5.
// r4 post-mortem: pullgemm2 = 363us at Occupancy 33% (grid 391 blocks = 1.5
// blocks/CU) -> gather latency-bound at 637 GB/s. Fix: M-tile 256->64, 256
// threads, grid 1563, LDS 18KB -> ~6 blocks/CU (~24 waves), 3x miss capacity.
// fused1 (fill ∥ gemm1) kept from r4 (worked: fill rides atomic latency).

constexpr int NN = 100000, RR = 4, EE = 800000;
constexpr int RN = RR * NN;
constexpr int CAP = 32;
constexpr int NG1 = (NN + 63) / 64;     // 1563 gemm1 tiles (M=64)
constexpr int NF  = RR * EE / 512;      // 6250 fill blocks (exact)

typedef short bf16x8 __attribute__((ext_vector_type(8)));
typedef float f32x4 __attribute__((ext_vector_type(4)));

__device__ inline unsigned short f2bf(float f) {
  unsigned u = __float_as_uint(f);
  u += 0x7FFF + ((u >> 16) & 1);
  return (unsigned short)(u >> 16);
}
__device__ inline float bf2f(unsigned short s) {
  return __uint_as_float(((unsigned)s) << 16);
}

// ---- weights -> bf16 [n][k]: BT1 [320][256], BT2 [80][64] ----
__global__ __launch_bounds__(256) void prep_w_kernel(const float* __restrict__ W1,
                                                     const float* __restrict__ L1w,
                                                     const float* __restrict__ W2,
                                                     const float* __restrict__ L2w,
                                                     unsigned short* __restrict__ BT1,
                                                     unsigned short* __restrict__ BT2) {
  int idx = blockIdx.x * 256 + threadIdx.x;
  if (idx < 320 * 256) {
    int n = idx >> 8, k = idx & 255;
    float v = (n < 256) ? W1[((size_t)((n >> 6) * 256 + k)) * 64 + (n & 63)]
                        : L1w[(size_t)k * 64 + (n - 256)];
    BT1[idx] = f2bf(v);
  } else {
    int j = idx - 320 * 256;
    if (j < 80 * 64) {
      int n = j >> 6, k = j & 63;
      float v = (n < 64) ? W2[((size_t)((n >> 4) * 64 + k)) * 16 + (n & 15)]
                         : L2w[(size_t)k * 16 + (n - 64)];
      BT2[j] = f2bf(v);
    }
  }
}

// ---- fused1: fill (padded CSR) + gemm1 ([1e5,320] = x @ BT1^T) ----
__global__ __launch_bounds__(512) void fused1_kernel(const float* __restrict__ x,
                                                     const unsigned short* __restrict__ BT1,
                                                     const float* __restrict__ L1b,
                                                     const int* __restrict__ src,
                                                     const int* __restrict__ dst,
                                                     int* __restrict__ cursor,
                                                     int* __restrict__ csr_pad,
                                                     unsigned short* __restrict__ hwcat,
                                                     float* __restrict__ h) {
  __shared__ char Al[64 * 64 * 2];    // 8 KB
  __shared__ char Bl[320 * 64 * 2];   // 40 KB
  const int bid = blockIdx.x;
  const bool is_gemm = (bid % 5 == 0) && (bid / 5 < NG1);

  if (!is_gemm) {
    int cnt = (bid + 4) / 5;
    if (cnt > NG1) cnt = NG1;
    int fid = bid - cnt;
    int fl = fid * 512 + threadIdx.x;   // 0..RR*EE-1 (exact)
    int r = fl / EE;
    int idx = r * NN + dst[fl];
    int pos = atomicAdd(&cursor[idx], 1);
    if (pos < CAP) csr_pad[(size_t)idx * CAP + pos] = src[fl];
    return;
  }

  const int t = threadIdx.x;
  const int m0 = (bid / 5) * 64;
  const int wid = t >> 6, lane = t & 63;
  const int wm = wid >> 2, wn = wid & 3;   // 2 x 4 wave grid
  const int l15 = lane & 15, g = lane >> 4;

  f32x4 acc[2][5];
#pragma unroll
  for (int i = 0; i < 2; ++i)
#pragma unroll
    for (int j = 0; j < 5; ++j) acc[i][j] = (f32x4){0.f, 0.f, 0.f, 0.f};

  for (int kc = 0; kc < 4; ++kc) {
    if (kc) __syncthreads();
#pragma unroll
    for (int it = 0; it < 2; ++it) {
      int fl = t + 512 * it;
      int row = fl >> 4, kq = (fl & 15) * 4;
      int rg = m0 + row;
      float4 v = (rg < NN) ? *(const float4*)(x + (size_t)rg * 256 + kc * 64 + kq)
                           : make_float4(0.f, 0.f, 0.f, 0.f);
      ushort4 pck = {f2bf(v.x), f2bf(v.y), f2bf(v.z), f2bf(v.w)};
      int wb = ((row * 64 + kq) * 2) ^ ((row & 7) << 4);
      *(ushort4*)(Al + wb) = pck;
    }
#pragma unroll
    for (int it = 0; it < 5; ++it) {
      int fl = t + 512 * it;
      int n = fl >> 3, i8 = (fl & 7) * 8;
      uint4 u = *(const uint4*)(BT1 + (size_t)n * 256 + kc * 64 + i8);
      int wb = ((n * 64 + i8) * 2) ^ ((n & 7) << 4);
      *(uint4*)(Bl + wb) = u;
    }
    __syncthreads();
#pragma unroll
    for (int ks = 0; ks < 2; ++ks) {
      bf16x8 af[2], bfr[5];
#pragma unroll
      for (int mi = 0; mi < 2; ++mi) {
        int row = wm * 32 + mi * 16 + l15;
        int byte = ((row * 64 + ks * 32 + g * 8) * 2) ^ ((row & 7) << 4);
        af[mi] = *(const bf16x8*)(Al + byte);
      }
#pragma unroll
      for (int ni = 0; ni < 5; ++ni) {
        int n = wn * 80 + ni * 16 + l15;
        int byte = ((n * 64 + ks * 32 + g * 8) * 2) ^ ((n & 7) << 4);
        bfr[ni] = *(const bf16x8*)(Bl + byte);
      }
#pragma unroll
      for (int mi = 0; mi < 2; ++mi)
#pragma unroll
        for (int ni = 0; ni < 5; ++ni)
          acc[mi][ni] = __builtin_amdgcn_mfma_f32_16x16x32_bf16(af[mi], bfr[ni], acc[mi][ni], 0, 0, 0);
    }
  }
#pragma unroll
  for (int mi = 0; mi < 2; ++mi) {
    int rbase = m0 + wm * 32 + mi * 16 + 4 * g;
#pragma unroll
    for (int ni = 0; ni < 5; ++ni) {
      int n0 = wn * 80 + ni * 16;
      int n = n0 + l15;
#pragma unroll
      for (int e = 0; e < 4; ++e) {
        int row = rbase + e;
        if (row >= NN) continue;
        float v = acc[mi][ni][e];
        if (n0 < 256) hwcat[(size_t)row * 256 + n] = f2bf(v);
        else h[(size_t)row * 64 + (n - 256)] = v + L1b[n - 256];
      }
    }
  }
}

// ---- pullgemm2: M-tile 64, 256 threads. Each wave pulls 16 rows (agg + self
//      + relu -> bf16 LDS), then [64,80] = A @ BT2^T. ----
__global__ __launch_bounds__(256) void pullgemm2_kernel(const float* __restrict__ h,
                                                        const unsigned short* __restrict__ hwcat,
                                                        const int* __restrict__ csr_pad,
                                                        const int* __restrict__ cursor,
                                                        const unsigned short* __restrict__ BT2,
                                                        const float* __restrict__ L2b,
                                                        unsigned short* __restrict__ hw2,
                                                        float* __restrict__ out) {
  __shared__ char Al[64 * 64 * 2];   // 8 KB
  __shared__ char Bl[80 * 64 * 2];   // 10 KB
  const int t = threadIdx.x;
  const int m0 = blockIdx.x * 64;
  const int wid = t >> 6, lane = t & 63;
  const int l15 = lane & 15, g = lane >> 4;

  // phase 1: wave wid pulls rows wid*16 .. wid*16+15
  for (int i = 0; i < 16; ++i) {
    int row = wid * 16 + i;
    int v = m0 + row;
    float hval = 0.f;
    if (v < NN) {
      hval = h[(size_t)v * 64 + lane];
#pragma unroll
      for (int r = 0; r < RR; ++r) {
        int idx = r * NN + v;
        int dcount = cursor[idx];
        int dd = dcount < CAP ? dcount : CAP;
        float w = 1.0f / (float)(dcount > 1 ? dcount : 1);
        const int* lst = csr_pad + (size_t)idx * CAP;
        float a = 0.f;
        int j = 0;
        for (; j + 4 <= dd; j += 4) {
          int s0 = lst[j], s1 = lst[j + 1], s2 = lst[j + 2], s3 = lst[j + 3];
          a += bf2f(hwcat[(size_t)s0 * 256 + r * 64 + lane]);
          a += bf2f(hwcat[(size_t)s1 * 256 + r * 64 + lane]);
          a += bf2f(hwcat[(size_t)s2 * 256 + r * 64 + lane]);
          a += bf2f(hwcat[(size_t)s3 * 256 + r * 64 + lane]);
        }
        for (; j < dd; ++j) a += bf2f(hwcat[(size_t)lst[j] * 256 + r * 64 + lane]);
        hval += a * w;
      }
      hval = fmaxf(hval, 0.f);
    }
    int wb = ((row * 64 + lane) * 2) ^ ((row & 7) << 4);
    *(unsigned short*)(Al + wb) = f2bf(hval);
  }
  // stage B: 80 x 64 bf16 = 640 uint4
#pragma unroll
  for (int it = 0; it < 3; ++it) {
    int fl = t + 256 * it;
    if (fl < 640) {
      int n = fl >> 3, i8 = (fl & 7) * 8;
      uint4 u = *(const uint4*)(BT2 + (size_t)n * 64 + i8);
      int wb = ((n * 64 + i8) * 2) ^ ((n & 7) << 4);
      *(uint4*)(Bl + wb) = u;
    }
  }
  __syncthreads();

  f32x4 acc[5];
#pragma unroll
  for (int j = 0; j < 5; ++j) acc[j] = (f32x4){0.f, 0.f, 0.f, 0.f};
#pragma unroll
  for (int ks = 0; ks < 2; ++ks) {
    bf16x8 af, bfr[5];
    {
      int row = wid * 16 + l15;
      int byte = ((row * 64 + ks * 32 + g * 8) * 2) ^ ((row & 7) << 4);
      af = *(const bf16x8*)(Al + byte);
    }
#pragma unroll
    for (int ni = 0; ni < 5; ++ni) {
      int n = ni * 16 + l15;
      int byte = ((n * 64 + ks * 32 + g * 8) * 2) ^ ((n & 7) << 4);
      bfr[ni] = *(const bf16x8*)(Bl + byte);
    }
#pragma unroll
    for (int ni = 0; ni < 5; ++ni)
      acc[ni] = __builtin_amdgcn_mfma_f32_16x16x32_bf16(af, bfr[ni], acc[ni], 0, 0, 0);
  }
  int rbase = m0 + wid * 16 + 4 * g;
#pragma unroll
  for (int ni = 0; ni < 5; ++ni) {
    int n0 = ni * 16;
    int n = n0 + l15;
#pragma unroll
    for (int e = 0; e < 4; ++e) {
      int row = rbase + e;
      if (row >= NN) continue;
      float v = acc[ni][e];
      if (n0 < 64) hw2[(size_t)row * 64 + n] = f2bf(v);
      else out[(size_t)row * 16 + (n - 64)] = v + L2b[n - 64];
    }
  }
}

// ---- pull layer2: out[v] += sum_r invdeg_r * sum_e hw2[src_e, r*16+c] ----
__global__ __launch_bounds__(256) void pull16_kernel(const unsigned short* __restrict__ hw2,
                                                     const int* __restrict__ csr_pad,
                                                     const int* __restrict__ cursor,
                                                     float* __restrict__ out) {
  int v = blockIdx.x * 4 + (threadIdx.x >> 6);
  if (v >= NN) return;
  int lane = threadIdx.x & 63;
  int c = lane & 15, g = lane >> 4;
  float tot = 0.f;
#pragma unroll
  for (int r = 0; r < RR; ++r) {
    int idx = r * NN + v;
    int d = cursor[idx];
    int dd = d < CAP ? d : CAP;
    float w = 1.0f / (float)(d > 1 ? d : 1);
    const int* lst = csr_pad + (size_t)idx * CAP;
    float acc = 0.f;
    for (int i = g; i < dd; i += 4) acc += bf2f(hw2[(size_t)lst[i] * 64 + r * 16 + c]);
    acc += __shfl_xor(acc, 16);
    acc += __shfl_xor(acc, 32);
    tot += acc * w;
  }
  if (lane < 16) out[(size_t)v * 16 + lane] += tot;
}

extern "C" void kernel_launch(void* const* d_in, const int* in_sizes, int n_in,
                              void* d_out, int out_size, void* d_ws, size_t ws_size,
                              hipStream_t stream) {
  const float* x   = (const float*)d_in[0];
  const int*   src = (const int*)d_in[1];
  const int*   dst = (const int*)d_in[2];
  const float* W1  = (const float*)d_in[3];
  const float* L1w = (const float*)d_in[4];
  const float* L1b = (const float*)d_in[5];
  const float* W2  = (const float*)d_in[6];
  const float* L2w = (const float*)d_in[7];
  const float* L2b = (const float*)d_in[8];
  float* out = (float*)d_out;

  char* p = (char*)d_ws;
  int* csr_pad = (int*)p;                     p += (size_t)RN * CAP * 4;      // 51.2 MB
  int* cursor  = (int*)p;                     p += (size_t)RN * 4;            // 1.6 MB
  unsigned short* hwcat = (unsigned short*)p; p += (size_t)NN * 256 * 2;      // 51.2 MB
  float* h = (float*)p;                       p += (size_t)NN * 64 * 4;       // 25.6 MB
  unsigned short* hw2 = (unsigned short*)p;   p += (size_t)NN * 64 * 2;       // 12.8 MB
  unsigned short* BT1 = (unsigned short*)p;   p += 320 * 256 * 2;
  unsigned short* BT2 = (unsigned short*)p;   p += 80 * 64 * 2;
  if ((size_t)(p - (char*)d_ws) > ws_size) return;  // visible fail (poison stays)

  hipMemsetAsync(cursor, 0, (size_t)RN * 4, stream);
  prep_w_kernel<<<(320 * 256 + 80 * 64 + 255) / 256, 256, 0, stream>>>(W1, L1w, W2, L2w, BT1, BT2);
  fused1_kernel<<<NG1 + NF, 512, 0, stream>>>(x, BT1, L1b, src, dst, cursor, csr_pad, hwcat, h);
  pullgemm2_kernel<<<(NN + 63) / 64, 256, 0, stream>>>(h, hwcat, csr_pad, cursor, BT2, L2b, hw2, out);
  pull16_kernel<<<(NN + 3) / 4, 256, 0, stream>>>(hw2, csr_pad, cursor, out);
}

// Round 6
// 403.160 us; speedup vs baseline: 37.7151x; 1.4761x over previous
//
#include <hip/hip_runtime.h>

// EntityClassify (R-GCN) — round 6: MLP-widened gather.
// r5 post-mortem: pullgemm2 completion rate 0.15 loads/cy/CU = 24 waves x 4
// outstanding / ~600cy latency -> concurrency-bound. Fix: [v][r] CSR layout
// (int4 degree load, contiguous 512B edge-list slot per node), all-4-relation
// interleaved gather with predicated index (loads always in-bounds), unroll 4
// -> up to 16 loads in flight per wave. Same for pull16 (lane-group=relation).

constexpr int NN = 100000, RR = 4, EE = 800000;
constexpr int RN = RR * NN;
constexpr int CAP = 32;
constexpr int NG1 = (NN + 63) / 64;     // 1563 gemm1 tiles (M=64)
constexpr int NF  = RR * EE / 512;      // 6250 fill blocks (exact)

typedef short bf16x8 __attribute__((ext_vector_type(8)));
typedef float f32x4 __attribute__((ext_vector_type(4)));

__device__ inline unsigned short f2bf(float f) {
  unsigned u = __float_as_uint(f);
  u += 0x7FFF + ((u >> 16) & 1);
  return (unsigned short)(u >> 16);
}
__device__ inline float bf2f(unsigned short s) {
  return __uint_as_float(((unsigned)s) << 16);
}

// ---- weights -> bf16 [n][k]: BT1 [320][256], BT2 [80][64] ----
__global__ __launch_bounds__(256) void prep_w_kernel(const float* __restrict__ W1,
                                                     const float* __restrict__ L1w,
                                                     const float* __restrict__ W2,
                                                     const float* __restrict__ L2w,
                                                     unsigned short* __restrict__ BT1,
                                                     unsigned short* __restrict__ BT2) {
  int idx = blockIdx.x * 256 + threadIdx.x;
  if (idx < 320 * 256) {
    int n = idx >> 8, k = idx & 255;
    float v = (n < 256) ? W1[((size_t)((n >> 6) * 256 + k)) * 64 + (n & 63)]
                        : L1w[(size_t)k * 64 + (n - 256)];
    BT1[idx] = f2bf(v);
  } else {
    int j = idx - 320 * 256;
    if (j < 80 * 64) {
      int n = j >> 6, k = j & 63;
      float v = (n < 64) ? W2[((size_t)((n >> 4) * 64 + k)) * 16 + (n & 15)]
                         : L2w[(size_t)k * 16 + (n - 64)];
      BT2[j] = f2bf(v);
    }
  }
}

// ---- fused1: fill (padded CSR, [v][r] layout) + gemm1 ----
__global__ __launch_bounds__(512) void fused1_kernel(const float* __restrict__ x,
                                                     const unsigned short* __restrict__ BT1,
                                                     const float* __restrict__ L1b,
                                                     const int* __restrict__ src,
                                                     const int* __restrict__ dst,
                                                     int* __restrict__ cursor,
                                                     int* __restrict__ csr_pad,
                                                     unsigned short* __restrict__ hwcat,
                                                     float* __restrict__ h) {
  __shared__ char Al[64 * 64 * 2];    // 8 KB
  __shared__ char Bl[320 * 64 * 2];   // 40 KB
  const int bid = blockIdx.x;
  const bool is_gemm = (bid % 5 == 0) && (bid / 5 < NG1);

  if (!is_gemm) {
    int cnt = (bid + 4) / 5;
    if (cnt > NG1) cnt = NG1;
    int fid = bid - cnt;
    int fl = fid * 512 + threadIdx.x;   // 0..RR*EE-1 (exact)
    int r = fl / EE;
    int idx = dst[fl] * RR + r;         // [v][r] layout
    int pos = atomicAdd(&cursor[idx], 1);
    if (pos < CAP) csr_pad[(size_t)idx * CAP + pos] = src[fl];
    return;
  }

  const int t = threadIdx.x;
  const int m0 = (bid / 5) * 64;
  const int wid = t >> 6, lane = t & 63;
  const int wm = wid >> 2, wn = wid & 3;   // 2 x 4 wave grid
  const int l15 = lane & 15, g = lane >> 4;

  f32x4 acc[2][5];
#pragma unroll
  for (int i = 0; i < 2; ++i)
#pragma unroll
    for (int j = 0; j < 5; ++j) acc[i][j] = (f32x4){0.f, 0.f, 0.f, 0.f};

  for (int kc = 0; kc < 4; ++kc) {
    if (kc) __syncthreads();
#pragma unroll
    for (int it = 0; it < 2; ++it) {
      int fl = t + 512 * it;
      int row = fl >> 4, kq = (fl & 15) * 4;
      int rg = m0 + row;
      float4 v = (rg < NN) ? *(const float4*)(x + (size_t)rg * 256 + kc * 64 + kq)
                           : make_float4(0.f, 0.f, 0.f, 0.f);
      ushort4 pck = {f2bf(v.x), f2bf(v.y), f2bf(v.z), f2bf(v.w)};
      int wb = ((row * 64 + kq) * 2) ^ ((row & 7) << 4);
      *(ushort4*)(Al + wb) = pck;
    }
#pragma unroll
    for (int it = 0; it < 5; ++it) {
      int fl = t + 512 * it;
      int n = fl >> 3, i8 = (fl & 7) * 8;
      uint4 u = *(const uint4*)(BT1 + (size_t)n * 256 + kc * 64 + i8);
      int wb = ((n * 64 + i8) * 2) ^ ((n & 7) << 4);
      *(uint4*)(Bl + wb) = u;
    }
    __syncthreads();
#pragma unroll
    for (int ks = 0; ks < 2; ++ks) {
      bf16x8 af[2], bfr[5];
#pragma unroll
      for (int mi = 0; mi < 2; ++mi) {
        int row = wm * 32 + mi * 16 + l15;
        int byte = ((row * 64 + ks * 32 + g * 8) * 2) ^ ((row & 7) << 4);
        af[mi] = *(const bf16x8*)(Al + byte);
      }
#pragma unroll
      for (int ni = 0; ni < 5; ++ni) {
        int n = wn * 80 + ni * 16 + l15;
        int byte = ((n * 64 + ks * 32 + g * 8) * 2) ^ ((n & 7) << 4);
        bfr[ni] = *(const bf16x8*)(Bl + byte);
      }
#pragma unroll
      for (int mi = 0; mi < 2; ++mi)
#pragma unroll
        for (int ni = 0; ni < 5; ++ni)
          acc[mi][ni] = __builtin_amdgcn_mfma_f32_16x16x32_bf16(af[mi], bfr[ni], acc[mi][ni], 0, 0, 0);
    }
  }
#pragma unroll
  for (int mi = 0; mi < 2; ++mi) {
    int rbase = m0 + wm * 32 + mi * 16 + 4 * g;
#pragma unroll
    for (int ni = 0; ni < 5; ++ni) {
      int n0 = wn * 80 + ni * 16;
      int n = n0 + l15;
#pragma unroll
      for (int e = 0; e < 4; ++e) {
        int row = rbase + e;
        if (row >= NN) continue;
        float v = acc[mi][ni][e];
        if (n0 < 256) hwcat[(size_t)row * 256 + n] = f2bf(v);
        else h[(size_t)row * 64 + (n - 256)] = v + L1b[n - 256];
      }
    }
  }
}

// ---- pullgemm2: M-tile 64, 256 threads; relation-interleaved gather ----
__global__ __launch_bounds__(256) void pullgemm2_kernel(const float* __restrict__ h,
                                                        const unsigned short* __restrict__ hwcat,
                                                        const int* __restrict__ csr_pad,
                                                        const int* __restrict__ cursor,
                                                        const unsigned short* __restrict__ BT2,
                                                        const float* __restrict__ L2b,
                                                        unsigned short* __restrict__ hw2,
                                                        float* __restrict__ out) {
  __shared__ char Al[64 * 64 * 2];   // 8 KB
  __shared__ char Bl[80 * 64 * 2];   // 10 KB
  const int t = threadIdx.x;
  const int m0 = blockIdx.x * 64;
  const int wid = t >> 6, lane = t & 63;
  const int l15 = lane & 15, g = lane >> 4;

  for (int i = 0; i < 16; ++i) {
    int row = wid * 16 + i;
    int v = m0 + row;
    float hval = 0.f;
    if (v < NN) {
      hval = h[(size_t)v * 64 + lane];
      int4 dg = *(const int4*)(cursor + v * 4);
      const int* lst = csr_pad + (size_t)v * (RR * CAP);
      int dd0 = dg.x < CAP ? dg.x : CAP, dd1 = dg.y < CAP ? dg.y : CAP;
      int dd2 = dg.z < CAP ? dg.z : CAP, dd3 = dg.w < CAP ? dg.w : CAP;
      float w0 = 1.0f / (float)(dg.x > 1 ? dg.x : 1);
      float w1 = 1.0f / (float)(dg.y > 1 ? dg.y : 1);
      float w2 = 1.0f / (float)(dg.z > 1 ? dg.z : 1);
      float w3 = 1.0f / (float)(dg.w > 1 ? dg.w : 1);
      int dmax = dd0 > dd1 ? dd0 : dd1;
      dmax = dmax > dd2 ? dmax : dd2;
      dmax = dmax > dd3 ? dmax : dd3;
      float a0 = 0.f, a1 = 0.f, a2 = 0.f, a3 = 0.f;
#pragma unroll 4
      for (int j = 0; j < dmax; ++j) {
        int e0 = lst[0 * CAP + j], e1 = lst[1 * CAP + j];
        int e2 = lst[2 * CAP + j], e3 = lst[3 * CAP + j];
        int s0 = (j < dd0) ? e0 : 0, s1 = (j < dd1) ? e1 : 0;
        int s2 = (j < dd2) ? e2 : 0, s3 = (j < dd3) ? e3 : 0;
        float f0 = bf2f(hwcat[(size_t)s0 * 256 + 0 * 64 + lane]);
        float f1 = bf2f(hwcat[(size_t)s1 * 256 + 1 * 64 + lane]);
        float f2 = bf2f(hwcat[(size_t)s2 * 256 + 2 * 64 + lane]);
        float f3 = bf2f(hwcat[(size_t)s3 * 256 + 3 * 64 + lane]);
        a0 += (j < dd0) ? f0 : 0.f;
        a1 += (j < dd1) ? f1 : 0.f;
        a2 += (j < dd2) ? f2 : 0.f;
        a3 += (j < dd3) ? f3 : 0.f;
      }
      hval += a0 * w0 + a1 * w1 + a2 * w2 + a3 * w3;
      hval = fmaxf(hval, 0.f);
    }
    int wb = ((row * 64 + lane) * 2) ^ ((row & 7) << 4);
    *(unsigned short*)(Al + wb) = f2bf(hval);
  }
  // stage B: 80 x 64 bf16 = 640 uint4
#pragma unroll
  for (int it = 0; it < 3; ++it) {
    int fl = t + 256 * it;
    if (fl < 640) {
      int n = fl >> 3, i8 = (fl & 7) * 8;
      uint4 u = *(const uint4*)(BT2 + (size_t)n * 64 + i8);
      int wb = ((n * 64 + i8) * 2) ^ ((n & 7) << 4);
      *(uint4*)(Bl + wb) = u;
    }
  }
  __syncthreads();

  f32x4 acc[5];
#pragma unroll
  for (int j = 0; j < 5; ++j) acc[j] = (f32x4){0.f, 0.f, 0.f, 0.f};
#pragma unroll
  for (int ks = 0; ks < 2; ++ks) {
    bf16x8 af, bfr[5];
    {
      int row = wid * 16 + l15;
      int byte = ((row * 64 + ks * 32 + g * 8) * 2) ^ ((row & 7) << 4);
      af = *(const bf16x8*)(Al + byte);
    }
#pragma unroll
    for (int ni = 0; ni < 5; ++ni) {
      int n = ni * 16 + l15;
      int byte = ((n * 64 + ks * 32 + g * 8) * 2) ^ ((n & 7) << 4);
      bfr[ni] = *(const bf16x8*)(Bl + byte);
    }
#pragma unroll
    for (int ni = 0; ni < 5; ++ni)
      acc[ni] = __builtin_amdgcn_mfma_f32_16x16x32_bf16(af, bfr[ni], acc[ni], 0, 0, 0);
  }
  int rbase = m0 + wid * 16 + 4 * g;
#pragma unroll
  for (int ni = 0; ni < 5; ++ni) {
    int n0 = ni * 16;
    int n = n0 + l15;
#pragma unroll
    for (int e = 0; e < 4; ++e) {
      int row = rbase + e;
      if (row >= NN) continue;
      float v = acc[ni][e];
      if (n0 < 64) hw2[(size_t)row * 64 + n] = f2bf(v);
      else out[(size_t)row * 16 + (n - 64)] = v + L2b[n - 64];
    }
  }
}

// ---- pull layer2: lane-group = relation; 4 concurrent lists ----
__global__ __launch_bounds__(256) void pull16_kernel(const unsigned short* __restrict__ hw2,
                                                     const int* __restrict__ csr_pad,
                                                     const int* __restrict__ cursor,
                                                     float* __restrict__ out) {
  int v = blockIdx.x * 4 + (threadIdx.x >> 6);
  if (v >= NN) return;
  int lane = threadIdx.x & 63;
  int c = lane & 15, g = lane >> 4;   // g = relation
  int4 dg = *(const int4*)(cursor + v * 4);
  int degg = (g == 0) ? dg.x : (g == 1) ? dg.y : (g == 2) ? dg.z : dg.w;
  int dd = degg < CAP ? degg : CAP;
  float w = 1.0f / (float)(degg > 1 ? degg : 1);
  int dd0 = dg.x < CAP ? dg.x : CAP, dd1 = dg.y < CAP ? dg.y : CAP;
  int dd2 = dg.z < CAP ? dg.z : CAP, dd3 = dg.w < CAP ? dg.w : CAP;
  int dmax = dd0 > dd1 ? dd0 : dd1;
  dmax = dmax > dd2 ? dmax : dd2;
  dmax = dmax > dd3 ? dmax : dd3;
  const int* lst = csr_pad + (size_t)v * (RR * CAP) + g * CAP;
  float a = 0.f;
#pragma unroll 4
  for (int j = 0; j < dmax; ++j) {
    int e = lst[j];
    int s = (j < dd) ? e : 0;
    float f = bf2f(hw2[(size_t)s * 64 + g * 16 + c]);
    a += (j < dd) ? f : 0.f;
  }
  a *= w;
  a += __shfl_xor(a, 16);
  a += __shfl_xor(a, 32);
  if (lane < 16) out[(size_t)v * 16 + lane] += a;
}

extern "C" void kernel_launch(void* const* d_in, const int* in_sizes, int n_in,
                              void* d_out, int out_size, void* d_ws, size_t ws_size,
                              hipStream_t stream) {
  const float* x   = (const float*)d_in[0];
  const int*   src = (const int*)d_in[1];
  const int*   dst = (const int*)d_in[2];
  const float* W1  = (const float*)d_in[3];
  const float* L1w = (const float*)d_in[4];
  const float* L1b = (const float*)d_in[5];
  const float* W2  = (const float*)d_in[6];
  const float* L2w = (const float*)d_in[7];
  const float* L2b = (const float*)d_in[8];
  float* out = (float*)d_out;

  char* p = (char*)d_ws;
  int* csr_pad = (int*)p;                     p += (size_t)RN * CAP * 4;      // 51.2 MB
  int* cursor  = (int*)p;                     p += (size_t)RN * 4;            // 1.6 MB
  unsigned short* hwcat = (unsigned short*)p; p += (size_t)NN * 256 * 2;      // 51.2 MB
  float* h = (float*)p;                       p += (size_t)NN * 64 * 4;       // 25.6 MB
  unsigned short* hw2 = (unsigned short*)p;   p += (size_t)NN * 64 * 2;       // 12.8 MB
  unsigned short* BT1 = (unsigned short*)p;   p += 320 * 256 * 2;
  unsigned short* BT2 = (unsigned short*)p;   p += 80 * 64 * 2;
  if ((size_t)(p - (char*)d_ws) > ws_size) return;  // visible fail (poison stays)

  hipMemsetAsync(cursor, 0, (size_t)RN * 4, stream);
  prep_w_kernel<<<(320 * 256 + 80 * 64 + 255) / 256, 256, 0, stream>>>(W1, L1w, W2, L2w, BT1, BT2);
  fused1_kernel<<<NG1 + NF, 512, 0, stream>>>(x, BT1, L1b, src, dst, cursor, csr_pad, hwcat, h);
  pullgemm2_kernel<<<(NN + 63) / 64, 256, 0, stream>>>(h, hwcat, csr_pad, cursor, BT2, L2b, hw2, out);
  pull16_kernel<<<(NN + 3) / 4, 256, 0, stream>>>(hw2, csr_pad, cursor, out);
}